// Round 1
// baseline (1112.065 us; speedup 1.0000x reference)
//
#include <hip/hip_runtime.h>

// ---------------------------------------------------------------------------
// LinearAggActor: y = mlp(x); a_k = agg_mean^k(y); logits = sum_k relu2(a_k)@M_k + c
// where M_k = w3 @ fc1_w_k @ fc2_w (16x8), c folds all biases. Softmax at end.
// CSR built per call (histogram + scan + fill); agg is gather-style, no float atomics.
// ---------------------------------------------------------------------------

__global__ void hist_k(const int* __restrict__ dst, int E, int n, int* __restrict__ counts) {
    int e = blockIdx.x * 256 + threadIdx.x;
    if (e < E) {
        int d = dst[e];
        if ((unsigned)d < (unsigned)n) atomicAdd(&counts[d], 1);
    }
}

// single-block scan: each thread serially sums a chunk, block-scan of 1024 partials,
// then serial exclusive write-out. offsets[n] = E total.
__global__ void scan_k(const int* __restrict__ counts, int* __restrict__ offsets,
                       int* __restrict__ cursor, int n) {
    const int T = 1024;
    __shared__ int tmp[T];
    int t = threadIdx.x;
    int chunk = (n + T - 1) / T;
    int beg = t * chunk;
    int end = beg + chunk; if (end > n) end = n; if (beg > n) beg = n;
    int s = 0;
    for (int i = beg; i < end; i++) s += counts[i];
    tmp[t] = s;
    __syncthreads();
    for (int off = 1; off < T; off <<= 1) {
        int v = (t >= off) ? tmp[t - off] : 0;
        __syncthreads();
        tmp[t] += v;
        __syncthreads();
    }
    int run = tmp[t] - s;   // exclusive prefix of this thread's chunk
    for (int i = beg; i < end; i++) {
        offsets[i] = run; cursor[i] = run; run += counts[i];
    }
    if (t == T - 1) offsets[n] = tmp[T - 1];
}

__global__ void fill_k(const int* __restrict__ src, const int* __restrict__ dst, int E, int n,
                       int* __restrict__ cursor, int* __restrict__ csr) {
    int e = blockIdx.x * 256 + threadIdx.x;
    if (e < E) {
        int d = dst[e];
        int s = src[e];
        if ((unsigned)d < (unsigned)n && (unsigned)s < (unsigned)n) {
            int p = atomicAdd(&cursor[d], 1);
            csr[p] = s;
        }
    }
}

// P = fc1_w @ fc2_w  : [512,8]
__global__ void pk_P(const float* __restrict__ fc1w, const float* __restrict__ fc2w,
                     float* __restrict__ P) {
    int idx = blockIdx.x * 64 + threadIdx.x;
    if (idx >= 512 * 8) return;
    int r = idx >> 3, j = idx & 7;
    float a = 0.f;
    for (int g = 0; g < 64; g++) a += fc1w[r * 64 + g] * fc2w[g * 8 + j];
    P[idx] = a;
}

// M[k][i][j] = sum_g w3[i][g] * P[k*64+g][j]   (1024 floats)
// cvec[j] = fc2_b[j] + fc1_b@fc2_w[:,j] + sum_k b3@P_k[:,j]
__global__ void pk_Mc(const float* __restrict__ w3, const float* __restrict__ b3,
                      const float* __restrict__ fc1b, const float* __restrict__ fc2w,
                      const float* __restrict__ fc2b, const float* __restrict__ P,
                      float* __restrict__ M, float* __restrict__ cvec) {
    int idx = blockIdx.x * 64 + threadIdx.x;
    if (idx < 1024) {
        int k = idx >> 7, i = (idx >> 3) & 15, j = idx & 7;
        float a = 0.f;
        for (int g = 0; g < 64; g++) a += w3[i * 64 + g] * P[(k * 64 + g) * 8 + j];
        M[idx] = a;
    } else if (idx < 1032) {
        int j = idx - 1024;
        float a = fc2b[j];
        for (int g = 0; g < 64; g++) a += fc1b[g] * fc2w[g * 8 + j];
        for (int r = 0; r < 512; r++) a += b3[r & 63] * P[r * 8 + j];
        cvec[j] = a;
    }
}

__global__ void init_logits_k(float* __restrict__ logits, const float* __restrict__ cvec, int total) {
    int i = blockIdx.x * 256 + threadIdx.x;
    if (i < total) logits[i] = cvec[i & 7];
}

// full MLP: y = relu(relu(x@w1+b1)@w2+b2)@w3+b3, one thread per node
__global__ __launch_bounds__(256) void mlp_full_k(
    const float* __restrict__ x, float* __restrict__ y,
    const float* __restrict__ w1, const float* __restrict__ b1,
    const float* __restrict__ w2, const float* __restrict__ b2,
    const float* __restrict__ w3, const float* __restrict__ b3, int n) {
    __shared__ float sw1[1024], sw2[256], sw3[1024], sb1[16], sb2[16], sb3[64];
    for (int i = threadIdx.x; i < 1024; i += 256) { sw1[i] = w1[i]; sw3[i] = w3[i]; }
    sw2[threadIdx.x] = w2[threadIdx.x & 255];
    if (threadIdx.x < 16) { sb1[threadIdx.x] = b1[threadIdx.x]; sb2[threadIdx.x] = b2[threadIdx.x]; }
    if (threadIdx.x < 64) sb3[threadIdx.x] = b3[threadIdx.x];
    __syncthreads();
    int nid = blockIdx.x * 256 + threadIdx.x;
    if (nid >= n) return;
    float xr[64];
    const float4* xp = (const float4*)(x + (size_t)nid * 64);
    #pragma unroll
    for (int i = 0; i < 16; i++) {
        float4 v = xp[i];
        xr[4 * i] = v.x; xr[4 * i + 1] = v.y; xr[4 * i + 2] = v.z; xr[4 * i + 3] = v.w;
    }
    float t1[16];
    #pragma unroll
    for (int j = 0; j < 16; j++) {
        float a = sb1[j];
        #pragma unroll
        for (int f = 0; f < 64; f++) a += xr[f] * sw1[f * 16 + j];
        t1[j] = fmaxf(a, 0.f);
    }
    float t2[16];
    #pragma unroll
    for (int j = 0; j < 16; j++) {
        float a = sb2[j];
        #pragma unroll
        for (int i = 0; i < 16; i++) a += t1[i] * sw2[i * 16 + j];
        t2[j] = fmaxf(a, 0.f);
    }
    float* yo = y + (size_t)nid * 64;
    #pragma unroll
    for (int g = 0; g < 64; g += 4) {
        float a0 = sb3[g], a1 = sb3[g + 1], a2 = sb3[g + 2], a3 = sb3[g + 3];
        #pragma unroll
        for (int j = 0; j < 16; j++) {
            float t = t2[j];
            a0 += t * sw3[j * 64 + g];
            a1 += t * sw3[j * 64 + g + 1];
            a2 += t * sw3[j * 64 + g + 2];
            a3 += t * sw3[j * 64 + g + 3];
        }
        float4 o; o.x = a0; o.y = a1; o.z = a2; o.w = a3;
        *(float4*)(yo + g) = o;
    }
}

// gather-mean: one wave per node, lane = feature
__global__ __launch_bounds__(256) void agg_k(
    const float* __restrict__ in, float* __restrict__ out,
    const int* __restrict__ offsets, const int* __restrict__ csr, int n) {
    int wave = threadIdx.x >> 6;
    int lane = threadIdx.x & 63;
    int node = blockIdx.x * 4 + wave;
    if (node >= n) return;
    int beg = offsets[node], end = offsets[node + 1];
    float acc = 0.f;
    int e = beg;
    for (; e + 1 < end; e += 2) {           // 2-way unroll: independent gathers in flight
        int s0 = csr[e], s1 = csr[e + 1];
        acc += in[(size_t)s0 * 64 + lane];
        acc += in[(size_t)s1 * 64 + lane];
    }
    if (e < end) {
        int s0 = csr[e];
        acc += in[(size_t)s0 * 64 + lane];
    }
    int cnt = end - beg;
    float denom = (float)(cnt > 0 ? cnt : 1);
    out[(size_t)node * 64 + lane] = acc / denom;
}

// field: logits[n] += relu2(a_n) @ M_k  (M_k is 16x8)
__global__ __launch_bounds__(256) void field_k(
    const float* __restrict__ a, float* __restrict__ logits,
    const float* __restrict__ w1, const float* __restrict__ b1,
    const float* __restrict__ w2, const float* __restrict__ b2,
    const float* __restrict__ M, int n) {
    __shared__ float sw1[1024], sw2[256], sb1[16], sb2[16], sM[128];
    for (int i = threadIdx.x; i < 1024; i += 256) sw1[i] = w1[i];
    sw2[threadIdx.x] = w2[threadIdx.x & 255];
    if (threadIdx.x < 128) sM[threadIdx.x] = M[threadIdx.x];
    if (threadIdx.x < 16) { sb1[threadIdx.x] = b1[threadIdx.x]; sb2[threadIdx.x] = b2[threadIdx.x]; }
    __syncthreads();
    int nid = blockIdx.x * 256 + threadIdx.x;
    if (nid >= n) return;
    float xr[64];
    const float4* xp = (const float4*)(a + (size_t)nid * 64);
    #pragma unroll
    for (int i = 0; i < 16; i++) {
        float4 v = xp[i];
        xr[4 * i] = v.x; xr[4 * i + 1] = v.y; xr[4 * i + 2] = v.z; xr[4 * i + 3] = v.w;
    }
    float t1[16];
    #pragma unroll
    for (int j = 0; j < 16; j++) {
        float acc = sb1[j];
        #pragma unroll
        for (int f = 0; f < 64; f++) acc += xr[f] * sw1[f * 16 + j];
        t1[j] = fmaxf(acc, 0.f);
    }
    float t2[16];
    #pragma unroll
    for (int j = 0; j < 16; j++) {
        float acc = sb2[j];
        #pragma unroll
        for (int i = 0; i < 16; i++) acc += t1[i] * sw2[i * 16 + j];
        t2[j] = fmaxf(acc, 0.f);
    }
    float* lp = logits + (size_t)nid * 8;
    #pragma unroll
    for (int j = 0; j < 8; j++) {
        float l = 0.f;
        #pragma unroll
        for (int i = 0; i < 16; i++) l += t2[i] * sM[i * 8 + j];
        lp[j] += l;
    }
}

__global__ void softmax_k(float* __restrict__ io, int n) {
    int nid = blockIdx.x * 256 + threadIdx.x;
    if (nid >= n) return;
    float4* p = (float4*)(io + (size_t)nid * 8);
    float4 v0 = p[0], v1 = p[1];
    float v[8] = {v0.x, v0.y, v0.z, v0.w, v1.x, v1.y, v1.z, v1.w};
    float m = v[0];
    #pragma unroll
    for (int j = 1; j < 8; j++) m = fmaxf(m, v[j]);
    float s = 0.f;
    #pragma unroll
    for (int j = 0; j < 8; j++) { v[j] = expf(v[j] - m); s += v[j]; }
    float inv = 1.f / s;
    v0.x = v[0] * inv; v0.y = v[1] * inv; v0.z = v[2] * inv; v0.w = v[3] * inv;
    v1.x = v[4] * inv; v1.y = v[5] * inv; v1.z = v[6] * inv; v1.w = v[7] * inv;
    p[0] = v0; p[1] = v1;
}

extern "C" void kernel_launch(void* const* d_in, const int* in_sizes, int n_in,
                              void* d_out, int out_size, void* d_ws, size_t ws_size,
                              hipStream_t stream) {
    const float* x    = (const float*)d_in[0];
    const int*   ei   = (const int*)d_in[1];      // edge_index (integer -> int*)
    const float* w1   = (const float*)d_in[2];
    const float* b1   = (const float*)d_in[3];
    const float* w2   = (const float*)d_in[4];
    const float* b2   = (const float*)d_in[5];
    const float* w3   = (const float*)d_in[6];
    const float* b3   = (const float*)d_in[7];
    const float* fc1w = (const float*)d_in[8];
    const float* fc1b = (const float*)d_in[9];
    const float* fc2w = (const float*)d_in[10];
    const float* fc2b = (const float*)d_in[11];
    float* out = (float*)d_out;

    int n = in_sizes[0] / 64;
    int E = in_sizes[1] / 2;
    const int* src = ei;
    const int* dst = ei + E;

    char* ws = (char*)d_ws;
    auto carve = [&](size_t bytes) {
        char* p = ws;
        ws += (bytes + 255) & ~((size_t)255);
        return p;
    };
    int*   counts  = (int*)carve((size_t)n * 4);
    int*   offsets = (int*)carve((size_t)(n + 1) * 4);
    int*   cursor  = (int*)carve((size_t)n * 4);
    int*   csr     = (int*)carve((size_t)E * 4);
    float* buf0    = (float*)carve((size_t)n * 64 * 4);
    float* buf1    = (float*)carve((size_t)n * 64 * 4);
    float* P       = (float*)carve(512 * 8 * 4);
    float* M       = (float*)carve(1024 * 4);
    float* cvec    = (float*)carve(8 * 4);

    hipMemsetAsync(counts, 0, (size_t)n * 4, stream);

    hist_k<<<(E + 255) / 256, 256, 0, stream>>>(dst, E, n, counts);
    scan_k<<<1, 1024, 0, stream>>>(counts, offsets, cursor, n);
    fill_k<<<(E + 255) / 256, 256, 0, stream>>>(src, dst, E, n, cursor, csr);

    pk_P<<<64, 64, 0, stream>>>(fc1w, fc2w, P);
    pk_Mc<<<17, 64, 0, stream>>>(w3, b3, fc1b, fc2w, fc2b, P, M, cvec);

    mlp_full_k<<<(n + 255) / 256, 256, 0, stream>>>(x, buf0, w1, b1, w2, b2, w3, b3, n);
    init_logits_k<<<(n * 8 + 255) / 256, 256, 0, stream>>>(out, cvec, n * 8);

    // field 0 on y = mlp(x)
    field_k<<<(n + 255) / 256, 256, 0, stream>>>(buf0, out, w1, b1, w2, b2, M, n);

    float* cur = buf0;
    float* nxt = buf1;
    for (int k = 1; k < 8; k++) {
        agg_k<<<(n + 3) / 4, 256, 0, stream>>>(cur, nxt, offsets, csr, n);
        field_k<<<(n + 255) / 256, 256, 0, stream>>>(nxt, out, w1, b1, w2, b2, M + k * 128, n);
        float* t = cur; cur = nxt; nxt = t;
    }

    softmax_k<<<(n + 255) / 256, 256, 0, stream>>>(out, n);
}

// Round 2
// 851.721 us; speedup vs baseline: 1.3057x; 1.3057x over previous
//
#include <hip/hip_runtime.h>

// ---------------------------------------------------------------------------
// LinearAggActor: y = mlp(x); a_k = agg_mean^k(y); logits = sum_k relu2(a_k)@M_k + c
// where M_k = w3 @ fc1_w_k @ fc2_w (16x8), c folds all biases. Softmax at end.
// CSR built per call (histogram + scan + fill); agg is gather-style, no float atomics.
// R1: agg_k 8-deep independent gather unroll (was 2) — latency-bound fix.
// ---------------------------------------------------------------------------

__global__ void hist_k(const int* __restrict__ dst, int E, int n, int* __restrict__ counts) {
    int e = blockIdx.x * 256 + threadIdx.x;
    if (e < E) {
        int d = dst[e];
        if ((unsigned)d < (unsigned)n) atomicAdd(&counts[d], 1);
    }
}

// single-block scan: each thread serially sums a chunk, block-scan of 1024 partials,
// then serial exclusive write-out. offsets[n] = E total.
__global__ void scan_k(const int* __restrict__ counts, int* __restrict__ offsets,
                       int* __restrict__ cursor, int n) {
    const int T = 1024;
    __shared__ int tmp[T];
    int t = threadIdx.x;
    int chunk = (n + T - 1) / T;
    int beg = t * chunk;
    int end = beg + chunk; if (end > n) end = n; if (beg > n) beg = n;
    int s = 0;
    for (int i = beg; i < end; i++) s += counts[i];
    tmp[t] = s;
    __syncthreads();
    for (int off = 1; off < T; off <<= 1) {
        int v = (t >= off) ? tmp[t - off] : 0;
        __syncthreads();
        tmp[t] += v;
        __syncthreads();
    }
    int run = tmp[t] - s;   // exclusive prefix of this thread's chunk
    for (int i = beg; i < end; i++) {
        offsets[i] = run; cursor[i] = run; run += counts[i];
    }
    if (t == T - 1) offsets[n] = tmp[T - 1];
}

__global__ void fill_k(const int* __restrict__ src, const int* __restrict__ dst, int E, int n,
                       int* __restrict__ cursor, int* __restrict__ csr) {
    int e = blockIdx.x * 256 + threadIdx.x;
    if (e < E) {
        int d = dst[e];
        int s = src[e];
        if ((unsigned)d < (unsigned)n && (unsigned)s < (unsigned)n) {
            int p = atomicAdd(&cursor[d], 1);
            csr[p] = s;
        }
    }
}

// P = fc1_w @ fc2_w  : [512,8]
__global__ void pk_P(const float* __restrict__ fc1w, const float* __restrict__ fc2w,
                     float* __restrict__ P) {
    int idx = blockIdx.x * 64 + threadIdx.x;
    if (idx >= 512 * 8) return;
    int r = idx >> 3, j = idx & 7;
    float a = 0.f;
    for (int g = 0; g < 64; g++) a += fc1w[r * 64 + g] * fc2w[g * 8 + j];
    P[idx] = a;
}

// M[k][i][j] = sum_g w3[i][g] * P[k*64+g][j]   (1024 floats)
// cvec[j] = fc2_b[j] + fc1_b@fc2_w[:,j] + sum_k b3@P_k[:,j]
__global__ void pk_Mc(const float* __restrict__ w3, const float* __restrict__ b3,
                      const float* __restrict__ fc1b, const float* __restrict__ fc2w,
                      const float* __restrict__ fc2b, const float* __restrict__ P,
                      float* __restrict__ M, float* __restrict__ cvec) {
    int idx = blockIdx.x * 64 + threadIdx.x;
    if (idx < 1024) {
        int k = idx >> 7, i = (idx >> 3) & 15, j = idx & 7;
        float a = 0.f;
        for (int g = 0; g < 64; g++) a += w3[i * 64 + g] * P[(k * 64 + g) * 8 + j];
        M[idx] = a;
    } else if (idx < 1032) {
        int j = idx - 1024;
        float a = fc2b[j];
        for (int g = 0; g < 64; g++) a += fc1b[g] * fc2w[g * 8 + j];
        for (int r = 0; r < 512; r++) a += b3[r & 63] * P[r * 8 + j];
        cvec[j] = a;
    }
}

__global__ void init_logits_k(float* __restrict__ logits, const float* __restrict__ cvec, int total) {
    int i = blockIdx.x * 256 + threadIdx.x;
    if (i < total) logits[i] = cvec[i & 7];
}

// full MLP: y = relu(relu(x@w1+b1)@w2+b2)@w3+b3, one thread per node
__global__ __launch_bounds__(256) void mlp_full_k(
    const float* __restrict__ x, float* __restrict__ y,
    const float* __restrict__ w1, const float* __restrict__ b1,
    const float* __restrict__ w2, const float* __restrict__ b2,
    const float* __restrict__ w3, const float* __restrict__ b3, int n) {
    __shared__ float sw1[1024], sw2[256], sw3[1024], sb1[16], sb2[16], sb3[64];
    for (int i = threadIdx.x; i < 1024; i += 256) { sw1[i] = w1[i]; sw3[i] = w3[i]; }
    sw2[threadIdx.x] = w2[threadIdx.x & 255];
    if (threadIdx.x < 16) { sb1[threadIdx.x] = b1[threadIdx.x]; sb2[threadIdx.x] = b2[threadIdx.x]; }
    if (threadIdx.x < 64) sb3[threadIdx.x] = b3[threadIdx.x];
    __syncthreads();
    int nid = blockIdx.x * 256 + threadIdx.x;
    if (nid >= n) return;
    float xr[64];
    const float4* xp = (const float4*)(x + (size_t)nid * 64);
    #pragma unroll
    for (int i = 0; i < 16; i++) {
        float4 v = xp[i];
        xr[4 * i] = v.x; xr[4 * i + 1] = v.y; xr[4 * i + 2] = v.z; xr[4 * i + 3] = v.w;
    }
    float t1[16];
    #pragma unroll
    for (int j = 0; j < 16; j++) {
        float a = sb1[j];
        #pragma unroll
        for (int f = 0; f < 64; f++) a += xr[f] * sw1[f * 16 + j];
        t1[j] = fmaxf(a, 0.f);
    }
    float t2[16];
    #pragma unroll
    for (int j = 0; j < 16; j++) {
        float a = sb2[j];
        #pragma unroll
        for (int i = 0; i < 16; i++) a += t1[i] * sw2[i * 16 + j];
        t2[j] = fmaxf(a, 0.f);
    }
    float* yo = y + (size_t)nid * 64;
    #pragma unroll
    for (int g = 0; g < 64; g += 4) {
        float a0 = sb3[g], a1 = sb3[g + 1], a2 = sb3[g + 2], a3 = sb3[g + 3];
        #pragma unroll
        for (int j = 0; j < 16; j++) {
            float t = t2[j];
            a0 += t * sw3[j * 64 + g];
            a1 += t * sw3[j * 64 + g + 1];
            a2 += t * sw3[j * 64 + g + 2];
            a3 += t * sw3[j * 64 + g + 3];
        }
        float4 o; o.x = a0; o.y = a1; o.z = a2; o.w = a3;
        *(float4*)(yo + g) = o;
    }
}

// gather-mean: one wave per node, lane = feature.
// 8 independent gathers in flight per wave (latency-bound fix).
__global__ __launch_bounds__(256) void agg_k(
    const float* __restrict__ in, float* __restrict__ out,
    const int* __restrict__ offsets, const int* __restrict__ csr, int n) {
    int wave = threadIdx.x >> 6;
    int lane = threadIdx.x & 63;
    int node = blockIdx.x * 4 + wave;
    if (node >= n) return;
    int beg = offsets[node], end = offsets[node + 1];
    float acc = 0.f;
    int e = beg;
    for (; e + 8 <= end; e += 8) {
        int s0 = csr[e], s1 = csr[e + 1], s2 = csr[e + 2], s3 = csr[e + 3];
        int s4 = csr[e + 4], s5 = csr[e + 5], s6 = csr[e + 6], s7 = csr[e + 7];
        float v0 = in[(size_t)s0 * 64 + lane];
        float v1 = in[(size_t)s1 * 64 + lane];
        float v2 = in[(size_t)s2 * 64 + lane];
        float v3 = in[(size_t)s3 * 64 + lane];
        float v4 = in[(size_t)s4 * 64 + lane];
        float v5 = in[(size_t)s5 * 64 + lane];
        float v6 = in[(size_t)s6 * 64 + lane];
        float v7 = in[(size_t)s7 * 64 + lane];
        acc += ((v0 + v1) + (v2 + v3)) + ((v4 + v5) + (v6 + v7));
    }
    for (; e < end; e++) {
        acc += in[(size_t)csr[e] * 64 + lane];
    }
    int cnt = end - beg;
    float denom = (float)(cnt > 0 ? cnt : 1);
    out[(size_t)node * 64 + lane] = acc / denom;
}

// field: logits[n] += relu2(a_n) @ M_k  (M_k is 16x8)
__global__ __launch_bounds__(256) void field_k(
    const float* __restrict__ a, float* __restrict__ logits,
    const float* __restrict__ w1, const float* __restrict__ b1,
    const float* __restrict__ w2, const float* __restrict__ b2,
    const float* __restrict__ M, int n) {
    __shared__ float sw1[1024], sw2[256], sb1[16], sb2[16], sM[128];
    for (int i = threadIdx.x; i < 1024; i += 256) sw1[i] = w1[i];
    sw2[threadIdx.x] = w2[threadIdx.x & 255];
    if (threadIdx.x < 128) sM[threadIdx.x] = M[threadIdx.x];
    if (threadIdx.x < 16) { sb1[threadIdx.x] = b1[threadIdx.x]; sb2[threadIdx.x] = b2[threadIdx.x]; }
    __syncthreads();
    int nid = blockIdx.x * 256 + threadIdx.x;
    if (nid >= n) return;
    float xr[64];
    const float4* xp = (const float4*)(a + (size_t)nid * 64);
    #pragma unroll
    for (int i = 0; i < 16; i++) {
        float4 v = xp[i];
        xr[4 * i] = v.x; xr[4 * i + 1] = v.y; xr[4 * i + 2] = v.z; xr[4 * i + 3] = v.w;
    }
    float t1[16];
    #pragma unroll
    for (int j = 0; j < 16; j++) {
        float acc = sb1[j];
        #pragma unroll
        for (int f = 0; f < 64; f++) acc += xr[f] * sw1[f * 16 + j];
        t1[j] = fmaxf(acc, 0.f);
    }
    float t2[16];
    #pragma unroll
    for (int j = 0; j < 16; j++) {
        float acc = sb2[j];
        #pragma unroll
        for (int i = 0; i < 16; i++) acc += t1[i] * sw2[i * 16 + j];
        t2[j] = fmaxf(acc, 0.f);
    }
    float* lp = logits + (size_t)nid * 8;
    #pragma unroll
    for (int j = 0; j < 8; j++) {
        float l = 0.f;
        #pragma unroll
        for (int i = 0; i < 16; i++) l += t2[i] * sM[i * 8 + j];
        lp[j] += l;
    }
}

__global__ void softmax_k(float* __restrict__ io, int n) {
    int nid = blockIdx.x * 256 + threadIdx.x;
    if (nid >= n) return;
    float4* p = (float4*)(io + (size_t)nid * 8);
    float4 v0 = p[0], v1 = p[1];
    float v[8] = {v0.x, v0.y, v0.z, v0.w, v1.x, v1.y, v1.z, v1.w};
    float m = v[0];
    #pragma unroll
    for (int j = 1; j < 8; j++) m = fmaxf(m, v[j]);
    float s = 0.f;
    #pragma unroll
    for (int j = 0; j < 8; j++) { v[j] = expf(v[j] - m); s += v[j]; }
    float inv = 1.f / s;
    v0.x = v[0] * inv; v0.y = v[1] * inv; v0.z = v[2] * inv; v0.w = v[3] * inv;
    v1.x = v[4] * inv; v1.y = v[5] * inv; v1.z = v[6] * inv; v1.w = v[7] * inv;
    p[0] = v0; p[1] = v1;
}

extern "C" void kernel_launch(void* const* d_in, const int* in_sizes, int n_in,
                              void* d_out, int out_size, void* d_ws, size_t ws_size,
                              hipStream_t stream) {
    const float* x    = (const float*)d_in[0];
    const int*   ei   = (const int*)d_in[1];      // edge_index (integer -> int*)
    const float* w1   = (const float*)d_in[2];
    const float* b1   = (const float*)d_in[3];
    const float* w2   = (const float*)d_in[4];
    const float* b2   = (const float*)d_in[5];
    const float* w3   = (const float*)d_in[6];
    const float* b3   = (const float*)d_in[7];
    const float* fc1w = (const float*)d_in[8];
    const float* fc1b = (const float*)d_in[9];
    const float* fc2w = (const float*)d_in[10];
    const float* fc2b = (const float*)d_in[11];
    float* out = (float*)d_out;

    int n = in_sizes[0] / 64;
    int E = in_sizes[1] / 2;
    const int* src = ei;
    const int* dst = ei + E;

    char* ws = (char*)d_ws;
    auto carve = [&](size_t bytes) {
        char* p = ws;
        ws += (bytes + 255) & ~((size_t)255);
        return p;
    };
    int*   counts  = (int*)carve((size_t)n * 4);
    int*   offsets = (int*)carve((size_t)(n + 1) * 4);
    int*   cursor  = (int*)carve((size_t)n * 4);
    int*   csr     = (int*)carve((size_t)E * 4);
    float* buf0    = (float*)carve((size_t)n * 64 * 4);
    float* buf1    = (float*)carve((size_t)n * 64 * 4);
    float* P       = (float*)carve(512 * 8 * 4);
    float* M       = (float*)carve(1024 * 4);
    float* cvec    = (float*)carve(8 * 4);

    hipMemsetAsync(counts, 0, (size_t)n * 4, stream);

    hist_k<<<(E + 255) / 256, 256, 0, stream>>>(dst, E, n, counts);
    scan_k<<<1, 1024, 0, stream>>>(counts, offsets, cursor, n);
    fill_k<<<(E + 255) / 256, 256, 0, stream>>>(src, dst, E, n, cursor, csr);

    pk_P<<<64, 64, 0, stream>>>(fc1w, fc2w, P);
    pk_Mc<<<17, 64, 0, stream>>>(w3, b3, fc1b, fc2w, fc2b, P, M, cvec);

    mlp_full_k<<<(n + 255) / 256, 256, 0, stream>>>(x, buf0, w1, b1, w2, b2, w3, b3, n);
    init_logits_k<<<(n * 8 + 255) / 256, 256, 0, stream>>>(out, cvec, n * 8);

    // field 0 on y = mlp(x)
    field_k<<<(n + 255) / 256, 256, 0, stream>>>(buf0, out, w1, b1, w2, b2, M, n);

    float* cur = buf0;
    float* nxt = buf1;
    for (int k = 1; k < 8; k++) {
        agg_k<<<(n + 3) / 4, 256, 0, stream>>>(cur, nxt, offsets, csr, n);
        field_k<<<(n + 255) / 256, 256, 0, stream>>>(nxt, out, w1, b1, w2, b2, M + k * 128, n);
        float* t = cur; cur = nxt; nxt = t;
    }

    softmax_k<<<(n + 255) / 256, 256, 0, stream>>>(out, n);
}

// Round 3
// 638.831 us; speedup vs baseline: 1.7408x; 1.3332x over previous
//
#include <hip/hip_runtime.h>

// ---------------------------------------------------------------------------
// LinearAggActor. R2:
//  - All aggregation done in 16-dim projected space: z0 = t2@(w3@w1)+b3@w1,
//    z_k = A^k z0 (A = mean-aggr, linear => commutes with @w1). 4x less traffic.
//  - fill_k writes csr via atomicExch (LLC-point op, no L2 line bouncing).
// logits = cvec + sum_k relu2(z_k) @ M_k ; softmax. M_k = w3@fc1_w_k@fc2_w.
// ---------------------------------------------------------------------------

__global__ void hist_k(const int* __restrict__ dst, int E, int n, int* __restrict__ counts) {
    int e = blockIdx.x * 256 + threadIdx.x;
    if (e < E) {
        int d = dst[e];
        if ((unsigned)d < (unsigned)n) atomicAdd(&counts[d], 1);
    }
}

__global__ void scan_k(const int* __restrict__ counts, int* __restrict__ offsets,
                       int* __restrict__ cursor, int n) {
    const int T = 1024;
    __shared__ int tmp[T];
    int t = threadIdx.x;
    int chunk = (n + T - 1) / T;
    int beg = t * chunk;
    int end = beg + chunk; if (end > n) end = n; if (beg > n) beg = n;
    int s = 0;
    for (int i = beg; i < end; i++) s += counts[i];
    tmp[t] = s;
    __syncthreads();
    for (int off = 1; off < T; off <<= 1) {
        int v = (t >= off) ? tmp[t - off] : 0;
        __syncthreads();
        tmp[t] += v;
        __syncthreads();
    }
    int run = tmp[t] - s;
    for (int i = beg; i < end; i++) {
        offsets[i] = run; cursor[i] = run; run += counts[i];
    }
    if (t == T - 1) offsets[n] = tmp[T - 1];
}

__global__ void fill_k(const int* __restrict__ src, const int* __restrict__ dst, int E, int n,
                       int* __restrict__ cursor, int* __restrict__ csr) {
    int e = blockIdx.x * 256 + threadIdx.x;
    if (e < E) {
        int d = dst[e];
        int s = src[e];
        if ((unsigned)d < (unsigned)n && (unsigned)s < (unsigned)n) {
            int p = atomicAdd(&cursor[d], 1);
            atomicExch(&csr[p], s);   // LLC-point write: no per-XCD line ownership churn
        }
    }
}

// P = fc1_w @ fc2_w  : [512,8]
__global__ void pk_P(const float* __restrict__ fc1w, const float* __restrict__ fc2w,
                     float* __restrict__ P) {
    int idx = blockIdx.x * 64 + threadIdx.x;
    if (idx >= 512 * 8) return;
    int r = idx >> 3, j = idx & 7;
    float a = 0.f;
    for (int g = 0; g < 64; g++) a += fc1w[r * 64 + g] * fc2w[g * 8 + j];
    P[idx] = a;
}

// idx<1024: M[k][i][j] = sum_g w3[i][g]*P[k*64+g][j]
// 1024..1031: cvec[j] = fc2_b[j] + fc1_b@fc2_w[:,j] + sum_r b3[r&63]*P[r][j]
// 1032..1287: W31[i][j] = sum_g w3[i*64+g]*w1[g*16+j]   (w3@w1, 16x16)
// 1288..1303: c31[j] = sum_g b3[g]*w1[g*16+j]
__global__ void pk_Mc(const float* __restrict__ w1, const float* __restrict__ w3,
                      const float* __restrict__ b3,
                      const float* __restrict__ fc1b, const float* __restrict__ fc2w,
                      const float* __restrict__ fc2b, const float* __restrict__ P,
                      float* __restrict__ M, float* __restrict__ cvec,
                      float* __restrict__ W31, float* __restrict__ c31) {
    int idx = blockIdx.x * 64 + threadIdx.x;
    if (idx < 1024) {
        int k = idx >> 7, i = (idx >> 3) & 15, j = idx & 7;
        float a = 0.f;
        for (int g = 0; g < 64; g++) a += w3[i * 64 + g] * P[(k * 64 + g) * 8 + j];
        M[idx] = a;
    } else if (idx < 1032) {
        int j = idx - 1024;
        float a = fc2b[j];
        for (int g = 0; g < 64; g++) a += fc1b[g] * fc2w[g * 8 + j];
        for (int r = 0; r < 512; r++) a += b3[r & 63] * P[r * 8 + j];
        cvec[j] = a;
    } else if (idx < 1288) {
        int t = idx - 1032, i = t >> 4, j = t & 15;
        float a = 0.f;
        for (int g = 0; g < 64; g++) a += w3[i * 64 + g] * w1[g * 16 + j];
        W31[t] = a;
    } else if (idx < 1304) {
        int j = idx - 1288;
        float a = 0.f;
        for (int g = 0; g < 64; g++) a += b3[g] * w1[g * 16 + j];
        c31[j] = a;
    }
}

__global__ void init_logits_k(float* __restrict__ logits, const float* __restrict__ cvec, int total) {
    int i = blockIdx.x * 256 + threadIdx.x;
    if (i < total) logits[i] = cvec[i & 7];
}

// x (n x 64) -> z0 (n x 16):  t1=relu(x@w1+b1); t2=relu(t1@w2+b2); z0=t2@W31+c31
__global__ __launch_bounds__(256) void mlp_proj_k(
    const float* __restrict__ x, float* __restrict__ z0,
    const float* __restrict__ w1, const float* __restrict__ b1,
    const float* __restrict__ w2, const float* __restrict__ b2,
    const float* __restrict__ W31, const float* __restrict__ c31, int n) {
    __shared__ float sw1[1024], sw2[256], sW[256], sb1[16], sb2[16], sc[16];
    for (int i = threadIdx.x; i < 1024; i += 256) sw1[i] = w1[i];
    sw2[threadIdx.x] = w2[threadIdx.x & 255];
    sW[threadIdx.x & 255] = W31[threadIdx.x & 255];
    if (threadIdx.x < 16) {
        sb1[threadIdx.x] = b1[threadIdx.x];
        sb2[threadIdx.x] = b2[threadIdx.x];
        sc[threadIdx.x] = c31[threadIdx.x];
    }
    __syncthreads();
    int nid = blockIdx.x * 256 + threadIdx.x;
    if (nid >= n) return;
    float xr[64];
    const float4* xp = (const float4*)(x + (size_t)nid * 64);
    #pragma unroll
    for (int i = 0; i < 16; i++) {
        float4 v = xp[i];
        xr[4 * i] = v.x; xr[4 * i + 1] = v.y; xr[4 * i + 2] = v.z; xr[4 * i + 3] = v.w;
    }
    float t1[16];
    #pragma unroll
    for (int j = 0; j < 16; j++) {
        float a = sb1[j];
        #pragma unroll
        for (int f = 0; f < 64; f++) a += xr[f] * sw1[f * 16 + j];
        t1[j] = fmaxf(a, 0.f);
    }
    float t2[16];
    #pragma unroll
    for (int j = 0; j < 16; j++) {
        float a = sb2[j];
        #pragma unroll
        for (int i = 0; i < 16; i++) a += t1[i] * sw2[i * 16 + j];
        t2[j] = fmaxf(a, 0.f);
    }
    float z[16];
    #pragma unroll
    for (int j = 0; j < 16; j++) {
        float a = sc[j];
        #pragma unroll
        for (int i = 0; i < 16; i++) a += t2[i] * sW[i * 16 + j];
        z[j] = a;
    }
    float4* zo = (float4*)(z0 + (size_t)nid * 16);
    #pragma unroll
    for (int q = 0; q < 4; q++) {
        float4 o; o.x = z[4 * q]; o.y = z[4 * q + 1]; o.z = z[4 * q + 2]; o.w = z[4 * q + 3];
        zo[q] = o;
    }
}

// gather-mean in 16-dim: one wave per node; 4 edge-slots x 16 feature-lanes.
// 4-deep unroll => 16 cache lines in flight per wave.
__global__ __launch_bounds__(256) void agg16_k(
    const float* __restrict__ in, float* __restrict__ out,
    const int* __restrict__ offsets, const int* __restrict__ csr, int n) {
    int node = (blockIdx.x * 256 + threadIdx.x) >> 6;
    int lane = threadIdx.x & 63;
    int g = lane >> 4, f = lane & 15;
    if (node >= n) return;
    int beg = offsets[node], end = offsets[node + 1];
    float acc = 0.f;
    int e = beg + g;
    for (; e + 12 < end; e += 16) {
        int s0 = csr[e], s1 = csr[e + 4], s2 = csr[e + 8], s3 = csr[e + 12];
        float v0 = in[(size_t)s0 * 16 + f];
        float v1 = in[(size_t)s1 * 16 + f];
        float v2 = in[(size_t)s2 * 16 + f];
        float v3 = in[(size_t)s3 * 16 + f];
        acc += (v0 + v1) + (v2 + v3);
    }
    for (; e < end; e += 4) {
        acc += in[(size_t)csr[e] * 16 + f];
    }
    acc += __shfl_down(acc, 32);
    acc += __shfl_down(acc, 16);
    if (g == 0) {
        int cnt = end - beg;
        out[(size_t)node * 16 + f] = acc / (float)(cnt > 0 ? cnt : 1);
    }
}

// field on z (n x 16): logits += relu(relu(z+b1)@w2+b2) @ M_k
__global__ __launch_bounds__(256) void field16_k(
    const float* __restrict__ z, float* __restrict__ logits,
    const float* __restrict__ w2, const float* __restrict__ b1,
    const float* __restrict__ b2, const float* __restrict__ M, int n) {
    __shared__ float sw2[256], sM[128], sb1[16], sb2[16];
    sw2[threadIdx.x] = w2[threadIdx.x & 255];
    if (threadIdx.x < 128) sM[threadIdx.x] = M[threadIdx.x];
    if (threadIdx.x < 16) { sb1[threadIdx.x] = b1[threadIdx.x]; sb2[threadIdx.x] = b2[threadIdx.x]; }
    __syncthreads();
    int nid = blockIdx.x * 256 + threadIdx.x;
    if (nid >= n) return;
    float h[16];
    const float4* zp = (const float4*)(z + (size_t)nid * 16);
    #pragma unroll
    for (int q = 0; q < 4; q++) {
        float4 v = zp[q];
        h[4 * q] = v.x; h[4 * q + 1] = v.y; h[4 * q + 2] = v.z; h[4 * q + 3] = v.w;
    }
    #pragma unroll
    for (int i = 0; i < 16; i++) h[i] = fmaxf(h[i] + sb1[i], 0.f);
    float t2[16];
    #pragma unroll
    for (int j = 0; j < 16; j++) {
        float a = sb2[j];
        #pragma unroll
        for (int i = 0; i < 16; i++) a += h[i] * sw2[i * 16 + j];
        t2[j] = fmaxf(a, 0.f);
    }
    float* lp = logits + (size_t)nid * 8;
    #pragma unroll
    for (int j = 0; j < 8; j++) {
        float l = 0.f;
        #pragma unroll
        for (int i = 0; i < 16; i++) l += t2[i] * sM[i * 8 + j];
        lp[j] += l;
    }
}

__global__ void softmax_k(float* __restrict__ io, int n) {
    int nid = blockIdx.x * 256 + threadIdx.x;
    if (nid >= n) return;
    float4* p = (float4*)(io + (size_t)nid * 8);
    float4 v0 = p[0], v1 = p[1];
    float v[8] = {v0.x, v0.y, v0.z, v0.w, v1.x, v1.y, v1.z, v1.w};
    float m = v[0];
    #pragma unroll
    for (int j = 1; j < 8; j++) m = fmaxf(m, v[j]);
    float s = 0.f;
    #pragma unroll
    for (int j = 0; j < 8; j++) { v[j] = expf(v[j] - m); s += v[j]; }
    float inv = 1.f / s;
    v0.x = v[0] * inv; v0.y = v[1] * inv; v0.z = v[2] * inv; v0.w = v[3] * inv;
    v1.x = v[4] * inv; v1.y = v[5] * inv; v1.z = v[6] * inv; v1.w = v[7] * inv;
    p[0] = v0; p[1] = v1;
}

extern "C" void kernel_launch(void* const* d_in, const int* in_sizes, int n_in,
                              void* d_out, int out_size, void* d_ws, size_t ws_size,
                              hipStream_t stream) {
    const float* x    = (const float*)d_in[0];
    const int*   ei   = (const int*)d_in[1];
    const float* w1   = (const float*)d_in[2];
    const float* b1   = (const float*)d_in[3];
    const float* w2   = (const float*)d_in[4];
    const float* b2   = (const float*)d_in[5];
    const float* w3   = (const float*)d_in[6];
    const float* b3   = (const float*)d_in[7];
    const float* fc1w = (const float*)d_in[8];
    const float* fc1b = (const float*)d_in[9];
    const float* fc2w = (const float*)d_in[10];
    const float* fc2b = (const float*)d_in[11];
    float* out = (float*)d_out;

    int n = in_sizes[0] / 64;
    int E = in_sizes[1] / 2;
    const int* src = ei;
    const int* dst = ei + E;

    char* ws = (char*)d_ws;
    auto carve = [&](size_t bytes) {
        char* p = ws;
        ws += (bytes + 255) & ~((size_t)255);
        return p;
    };
    int*   counts  = (int*)carve((size_t)n * 4);
    int*   offsets = (int*)carve((size_t)(n + 1) * 4);
    int*   cursor  = (int*)carve((size_t)n * 4);
    int*   csr     = (int*)carve((size_t)E * 4);
    float* buf0    = (float*)carve((size_t)n * 16 * 4);
    float* buf1    = (float*)carve((size_t)n * 16 * 4);
    float* P       = (float*)carve(512 * 8 * 4);
    float* M       = (float*)carve(1024 * 4);
    float* cvec    = (float*)carve(8 * 4);
    float* W31     = (float*)carve(256 * 4);
    float* c31     = (float*)carve(16 * 4);

    hipMemsetAsync(counts, 0, (size_t)n * 4, stream);

    hist_k<<<(E + 255) / 256, 256, 0, stream>>>(dst, E, n, counts);
    scan_k<<<1, 1024, 0, stream>>>(counts, offsets, cursor, n);
    fill_k<<<(E + 255) / 256, 256, 0, stream>>>(src, dst, E, n, cursor, csr);

    pk_P<<<64, 64, 0, stream>>>(fc1w, fc2w, P);
    pk_Mc<<<21, 64, 0, stream>>>(w1, w3, b3, fc1b, fc2w, fc2b, P, M, cvec, W31, c31);

    mlp_proj_k<<<(n + 255) / 256, 256, 0, stream>>>(x, buf0, w1, b1, w2, b2, W31, c31, n);
    init_logits_k<<<(n * 8 + 255) / 256, 256, 0, stream>>>(out, cvec, n * 8);

    field16_k<<<(n + 255) / 256, 256, 0, stream>>>(buf0, out, w2, b1, b2, M, n);

    float* cur = buf0;
    float* nxt = buf1;
    for (int k = 1; k < 8; k++) {
        agg16_k<<<(n + 3) / 4, 256, 0, stream>>>(cur, nxt, offsets, csr, n);
        field16_k<<<(n + 255) / 256, 256, 0, stream>>>(nxt, out, w2, b1, b2, M + k * 128, n);
        float* t = cur; cur = nxt; nxt = t;
    }

    softmax_k<<<(n + 255) / 256, 256, 0, stream>>>(out, n);
}